// Round 8
// baseline (315.235 us; speedup 1.0000x reference)
//
#include <hip/hip_runtime.h>
#include <math.h>

// Problem dims
constexpr int B   = 16;
constexpr int K   = 64;
constexpr int BK  = B * K;        // 1024
constexpr int IN  = 128;
constexpr int H0  = 192;
constexpr int H1  = 64;
constexpr int UNF = 6;
constexpr float EPS = 1e-8f;
constexpr float DT  = 1.0f / 6.0f;
constexpr float L2E = 1.4426950408889634f;   // log2(e)

static __device__ __forceinline__ float rcpf(float x) {
    return __builtin_amdgcn_rcpf(x);
}
static __device__ __forceinline__ float exp2_fast(float x) {
#if __has_builtin(__builtin_amdgcn_exp2f)
    return __builtin_amdgcn_exp2f(x);   // v_exp_f32
#else
    return exp2f(x);
#endif
}
// sigmoid(z) with z pre-scaled by log2(e): s = 1/(1+2^(-z2)); t = -z2
static __device__ __forceinline__ float sig_from_t(float t) {
    return rcpf(1.0f + exp2_fast(t));
}

// 4 rows of sigmoid-synapse accumulate for one (i,h) pack element.
static __device__ __forceinline__ void rows4(const float4 p, const float4 vv,
                                             float num[4], float den[4]) {
    float s;
    s = sig_from_t(fmaf(-p.y, vv.x, p.z));
    num[0] = fmaf(s, p.w, num[0]); den[0] = fmaf(s, p.x, den[0]);
    s = sig_from_t(fmaf(-p.y, vv.y, p.z));
    num[1] = fmaf(s, p.w, num[1]); den[1] = fmaf(s, p.x, den[1]);
    s = sig_from_t(fmaf(-p.y, vv.z, p.z));
    num[2] = fmaf(s, p.w, num[2]); den[2] = fmaf(s, p.x, den[2]);
    s = sig_from_t(fmaf(-p.y, vv.w, p.z));
    num[3] = fmaf(s, p.w, num[3]); den[3] = fmaf(s, p.x, den[3]);
}

// ---------------------------------------------------------------------------
// Prep: (a) pack {relu(w), sig*L2E, sig*mu*L2E, relu(w)*erev} into float4 for
// the three hot matrices; (b) layer-0 input synapse sums [B,H0] (x is shared
// by all K particles and all 6 steps). One kernel, branch on blockIdx.
constexpr int NPACK    = H0 * H0 + H0 * H1 + H1 * H1;  // 53248
constexpr int NPACKBLK = NPACK / 256;                   // 208
__global__ __launch_bounds__(256) void prep_kernel(
    const float* __restrict__ w0,  const float* __restrict__ sig0,
    const float* __restrict__ mu0, const float* __restrict__ erev0,
    const float* __restrict__ iw1, const float* __restrict__ isig1,
    const float* __restrict__ imu1,const float* __restrict__ ierev1,
    const float* __restrict__ w1,  const float* __restrict__ sig1,
    const float* __restrict__ mu1, const float* __restrict__ erev1,
    const float* __restrict__ x,   const float* __restrict__ iw0,
    const float* __restrict__ isig0,const float* __restrict__ imu0,
    const float* __restrict__ ierev0,
    float4* __restrict__ pack0, float4* __restrict__ packi1,
    float4* __restrict__ pack1,
    float* __restrict__ in_num, float* __restrict__ in_den)
{
    __shared__ float xs[IN];
    if (blockIdx.x < NPACKBLK) {
        const int t = blockIdx.x * 256 + threadIdx.x;
        constexpr int N0 = H0 * H0;          // 36864
        constexpr int N1 = H0 * H1;          // 12288
        if (t < N0) {
            const float wv = fmaxf(w0[t], 0.0f);
            pack0[t] = make_float4(wv, sig0[t] * L2E, sig0[t] * mu0[t] * L2E,
                                   wv * erev0[t]);
        } else if (t < N0 + N1) {
            const int u = t - N0;
            const float wv = fmaxf(iw1[u], 0.0f);
            packi1[u] = make_float4(wv, isig1[u] * L2E,
                                    isig1[u] * imu1[u] * L2E, wv * ierev1[u]);
        } else {
            const int u = t - N0 - N1;
            const float wv = fmaxf(w1[u], 0.0f);
            pack1[u] = make_float4(wv, sig1[u] * L2E, sig1[u] * mu1[u] * L2E,
                                   wv * erev1[u]);
        }
    } else {
        const int b = blockIdx.x - NPACKBLK;
        const int h = threadIdx.x;
        if (h < IN) xs[h] = x[b * IN + h];
        __syncthreads();
        if (h < H0) {
            float num = 0.0f, den = 0.0f;
            #pragma unroll 4
            for (int i = 0; i < IN; ++i) {
                const int idx = i * H0 + h;
                const float wv = fmaxf(iw0[idx], 0.0f);
                const float t  = isig0[idx] * L2E * (imu0[idx] - xs[i]);
                const float a  = wv * sig_from_t(t);
                num = fmaf(a, ierev0[idx], num);
                den += a;
            }
            in_num[b * H0 + h] = num;
            in_den[b * H0 + h] = den;
        }
    }
}

// ---------------------------------------------------------------------------
// Fused unfold + output: 256 blocks x 768 threads, ONE block/CU.
//
// __launch_bounds__(768, 3): the second arg (min waves per EU = 3, i.e. 12
// waves/CU) is THE critical piece — without it the backend targets 6
// waves/EU and caps VGPRs at ~84, spilling the persistent pack registers to
// scratch (R6: WRITE 79 MB @ VGPR=64; R7: WRITE 95 MB @ VGPR=84). With it
// the allocator gets the full ~168-VGPR budget for our actual occupancy.
//
// Layer 0: subgroup q in 0..3 (192 thr) owns i in [48q,48q+48) for ALL 4
// rows: 16 i's persistent in pr[16] (loaded once, reused 6 steps — giving
// each wave ~800cy of load-free work right after every barrier), 32 i's
// streamed from L2. State transposed vs[i][4] (one wave-uniform ds_read_b128
// = all 4 rows). Partials via LDS; every thread updates (row q, elem h).
// Layer 1: input-syn over s0 split 12 ways (one-shot); recurrent matrix
// fully register-resident (pr1[8], waves 0..7); update on waves 0..3.
__global__ __launch_bounds__(768, 3) void fused_unfold_kernel(
    const float* __restrict__ particles,  // [BK, 256]
    const float* __restrict__ noise0,     // [UNF, BK, H0]
    const float* __restrict__ noise1,     // [UNF, BK, H1]
    const float* __restrict__ log_weights,// [B, K]
    const float* __restrict__ gleak0, const float* __restrict__ vleak0,
    const float* __restrict__ cm0,    const float* __restrict__ gdiff0,
    const float* __restrict__ gleak1, const float* __restrict__ vleak1,
    const float* __restrict__ cm1,    const float* __restrict__ gdiff1,
    const float4* __restrict__ pack0,     // [H0*H0]
    const float4* __restrict__ packi1,    // [H0*H1]
    const float4* __restrict__ pack1,     // [H1*H1]
    const float* __restrict__ in_num,     // [B, H0]
    const float* __restrict__ in_den,
    float* __restrict__ outp,             // new_particles region: [BK, 256]
    float* __restrict__ out_y,            // [B, H1] — pre-zeroed
    float* __restrict__ out_lw)           // [B, K]
{
    const int tid = threadIdx.x;
    const int h   = tid % H0;             // 0..191
    const int q   = tid / H0;             // 0..3 (i-split group == owned row)
    const int bk0 = blockIdx.x * 4;
    const int b   = blockIdx.x >> 4;      // batch (16 blocks per batch)
    const int k0  = (blockIdx.x & 15) * 4;// this block's first k within batch

    const int h1  = tid & 63;
    const int qq  = tid >> 6;             // wave id 0..11

    __shared__ __align__(16) float vs[H0][4];     // s0 state, [i][m]
    __shared__ float2 part0[4][4][H0];            // [q][m][h] {num,den}
    __shared__ __align__(16) float v1s[H1][4];    // s1 state, [i][m]
    __shared__ float2 part1[12][4][H1];           // [slot][m][h1]
    __shared__ float  w4[4];                      // softmax weights, this block

    // ---- Softmax weights + log_weights passthrough (wave 0) ----
    if (tid < 64) {
        const float lw = log_weights[b * K + tid];
        out_lw[b * K + tid] = lw;                 // 16x redundant, same value
        float mx = lw;
        #pragma unroll
        for (int o = 32; o > 0; o >>= 1) mx = fmaxf(mx, __shfl_xor(mx, o));
        const float e = __expf(lw - mx);
        float ssum = e;
        #pragma unroll
        for (int o = 32; o > 0; o >>= 1) ssum += __shfl_xor(ssum, o);
        if (tid >= k0 && tid < k0 + 4) w4[tid - k0] = e / ssum;
    }

    // ---- Early layer-1 state loads (hidden behind layer-0 compute) ----
    float nz1[UNF];
    if (tid < 256) {                      // qq in 0..3 = row
        v1s[h1][qq] = particles[(bk0 + qq) * 256 + H0 + h1];
        #pragma unroll
        for (int s = 0; s < UNF; ++s)
            nz1[s] = noise1[s * (BK * H1) + (bk0 + qq) * H1 + h1];
    }

    // ---- Layer 0 setup (all 768 threads: 4 rows x 192 h) ----
    vs[h][q] = particles[(bk0 + q) * 256 + h];
    float nz[UNF];
    #pragma unroll
    for (int s = 0; s < UNF; ++s)
        nz[s] = noise0[s * (BK * H0) + (bk0 + q) * H0 + h];

    const float gl    = fmaxf(gleak0[h], 0.0f);
    const float glvl  = gl * vleak0[h];
    const float cinv  = rcpf(fmaxf(cm0[h], 0.0f) + EPS);
    const float gd    = gdiff0[h] * sqrtf(DT);
    const float innum = in_num[b * H0 + h];
    const float inden = in_den[b * H0 + h];

    // Persistent pack registers: first 16 of this thread's 48 i's. Loaded
    // once, reused in all 6 steps (pack is step-invariant). 64 VGPRs.
    const float4* pp = pack0 + (size_t)(48 * q) * H0 + h;
    float4 pr[16];
    #pragma unroll
    for (int j = 0; j < 16; ++j) pr[j] = pp[(size_t)j * H0];
    const float4* ps = pp + (size_t)16 * H0;      // streamed remainder (32)

    const float4* vs4 = (const float4*)&vs[0][0];
    __syncthreads();

    // ---- Layer 0 unfold ----
    for (int step = 0; step < UNF; ++step) {
        float num[4] = {0.f, 0.f, 0.f, 0.f};
        float den[4] = {0.f, 0.f, 0.f, 0.f};
        // register-resident part: issuable immediately after the barrier,
        // covers the stream loads' L2 latency
        #pragma unroll
        for (int j = 0; j < 16; ++j)
            rows4(pr[j], vs4[48 * q + j], num, den);
        // streamed part
        #pragma unroll 8
        for (int ii = 0; ii < 32; ++ii)
            rows4(ps[(size_t)ii * H0], vs4[48 * q + 16 + ii], num, den);

        #pragma unroll
        for (int m = 0; m < 4; ++m)
            part0[q][m][h] = make_float2(num[m], den[m]);
        __syncthreads();
        // thread (q,h) updates row q, element h — all 768 threads active
        float tn = innum, td = inden;
        #pragma unroll
        for (int j = 0; j < 4; ++j) {
            const float2 t = part0[j][q][h];
            tn += t.x; td += t.y;
        }
        const float vh = vs[h][q];
        const float d  = (glvl + tn - (gl + td) * vh) * cinv;
        vs[h][q] = fmaf(gd, nz[step], fmaf(d, DT, vh));
        __syncthreads();
    }

    // s0 -> new_particles[:, :H0] (own value; no barrier needed)
    outp[(bk0 + q) * 256 + h] = vs[h][q];

    // ---- Layer 1 (same 4 rows; s0 in LDS) ----
    const float gl1   = fmaxf(gleak1[h1], 0.0f);
    const float glvl1 = gl1 * vleak1[h1];
    const float cinv1 = rcpf(fmaxf(cm1[h1], 0.0f) + EPS);
    const float gd1   = gdiff1[h1] * sqrtf(DT);

    // l1 recurrent matrix: fully register-resident for waves 0..7 (pr1[8]),
    // issued here so the loads overlap the input-synapse sweep below.
    float4 pr1[8];
    if (tid < 512) {
        #pragma unroll
        for (int j = 0; j < 8; ++j)
            pr1[j] = pack1[(qq * 8 + j) * H1 + h1];
    }

    // Input synapse over s0: 12 waves x 16 i, step-invariant.
    float in1n[4] = {0.f, 0.f, 0.f, 0.f};
    float in1d[4] = {0.f, 0.f, 0.f, 0.f};
    #pragma unroll 4
    for (int ii = 0; ii < 16; ++ii) {
        const int i = qq * 16 + ii;
        rows4(packi1[i * H1 + h1], vs4[i], in1n, in1d);
    }
    if (tid >= 512) {                     // waves 8..11: deposit once
        #pragma unroll
        for (int m = 0; m < 4; ++m)
            part1[qq][m][h1] = make_float2(in1n[m], in1d[m]);
    }
    __syncthreads();

    for (int step = 0; step < UNF; ++step) {
        if (tid < 512) {                  // waves 0..7: recurrent, 8 i each
            float num[4], den[4];
            #pragma unroll
            for (int m = 0; m < 4; ++m) { num[m] = in1n[m]; den[m] = in1d[m]; }
            #pragma unroll
            for (int ii = 0; ii < 8; ++ii)
                rows4(pr1[ii], *(const float4*)&v1s[qq * 8 + ii][0], num, den);
            #pragma unroll
            for (int m = 0; m < 4; ++m)
                part1[qq][m][h1] = make_float2(num[m], den[m]);
        }
        __syncthreads();
        if (tid < 256) {                  // row qq, element h1
            float tn = 0.f, td = 0.f;
            #pragma unroll
            for (int j = 0; j < 12; ++j) {
                const float2 t = part1[j][qq][h1];
                tn += t.x; td += t.y;
            }
            const float vh = v1s[h1][qq];
            const float d  = (glvl1 + tn - (gl1 + td) * vh) * cinv1;
            v1s[h1][qq] = fmaf(gd1, nz1[step], fmaf(d, DT, vh));
        }
        __syncthreads();
    }

    if (tid < 256)
        outp[(bk0 + qq) * 256 + H0 + h1] = v1s[h1][qq];  // s1 -> [:, H0:]

    // ---- Weighted-mean contribution of this block's 4 particles ----
    if (tid < 64) {
        const float acc = w4[0] * v1s[tid][0] + w4[1] * v1s[tid][1]
                        + w4[2] * v1s[tid][2] + w4[3] * v1s[tid][3];
        atomicAdd(&out_y[b * H1 + tid], acc);
    }
}

// ---------------------------------------------------------------------------
extern "C" void kernel_launch(void* const* d_in, const int* in_sizes, int n_in,
                              void* d_out, int out_size, void* d_ws, size_t ws_size,
                              hipStream_t stream) {
    const float* x           = (const float*)d_in[0];
    const float* particles   = (const float*)d_in[1];
    const float* log_weights = (const float*)d_in[2];
    const float* noise0      = (const float*)d_in[3];
    const float* noise1      = (const float*)d_in[4];
    const float* gleak0 = (const float*)d_in[5];
    const float* vleak0 = (const float*)d_in[6];
    const float* cm0    = (const float*)d_in[7];
    const float* iw0    = (const float*)d_in[8];
    const float* isig0  = (const float*)d_in[9];
    const float* imu0   = (const float*)d_in[10];
    const float* ierev0 = (const float*)d_in[11];
    const float* w0     = (const float*)d_in[12];
    const float* sig0   = (const float*)d_in[13];
    const float* mu0    = (const float*)d_in[14];
    const float* erev0  = (const float*)d_in[15];
    const float* gdiff0 = (const float*)d_in[16];
    const float* gleak1 = (const float*)d_in[17];
    const float* vleak1 = (const float*)d_in[18];
    const float* cm1    = (const float*)d_in[19];
    const float* iw1    = (const float*)d_in[20];
    const float* isig1  = (const float*)d_in[21];
    const float* imu1   = (const float*)d_in[22];
    const float* ierev1 = (const float*)d_in[23];
    const float* w1     = (const float*)d_in[24];
    const float* sig1   = (const float*)d_in[25];
    const float* mu1    = (const float*)d_in[26];
    const float* erev1  = (const float*)d_in[27];
    const float* gdiff1 = (const float*)d_in[28];

    float* out    = (float*)d_out;
    float* out_y  = out;                       // [B, H1] = 1024
    float* out_np = out + B * H1;              // [BK, 256] = 262144
    float* out_lw = out + B * H1 + BK * 256;   // [B, K]   = 1024

    // Workspace layout (floats): pack0 | packi1 | pack1 | in_num0 | in_den0
    float* ws      = (float*)d_ws;
    float4* pack0  = (float4*)(ws);                       // 36864 float4
    float4* packi1 = (float4*)(ws + 4 * 36864);           // 12288 float4
    float4* pack1  = (float4*)(ws + 4 * (36864 + 12288)); //  4096 float4
    float*  in_num0 = ws + 4 * (36864 + 12288 + 4096);    // [B, H0]
    float*  in_den0 = in_num0 + B * H0;                   // [B, H0]

    // out_y accumulated via atomics — zero it (d_out is poisoned pre-call).
    hipMemsetAsync(out_y, 0, B * H1 * sizeof(float), stream);

    prep_kernel<<<NPACKBLK + B, 256, 0, stream>>>(
        w0, sig0, mu0, erev0, iw1, isig1, imu1, ierev1, w1, sig1, mu1, erev1,
        x, iw0, isig0, imu0, ierev0,
        pack0, packi1, pack1, in_num0, in_den0);

    fused_unfold_kernel<<<BK / 4, 768, 0, stream>>>(
        particles, noise0, noise1, log_weights,
        gleak0, vleak0, cm0, gdiff0,
        gleak1, vleak1, cm1, gdiff1,
        pack0, packi1, pack1, in_num0, in_den0,
        out_np, out_y, out_lw);
}

// Round 9
// 311.381 us; speedup vs baseline: 1.0124x; 1.0124x over previous
//
#include <hip/hip_runtime.h>
#include <math.h>

// Problem dims
constexpr int B   = 16;
constexpr int K   = 64;
constexpr int BK  = B * K;        // 1024
constexpr int IN  = 128;
constexpr int H0  = 192;
constexpr int H1  = 64;
constexpr int UNF = 6;
constexpr float EPS = 1e-8f;
constexpr float DT  = 1.0f / 6.0f;
constexpr float L2E = 1.4426950408889634f;   // log2(e)

static __device__ __forceinline__ float rcpf(float x) {
    return __builtin_amdgcn_rcpf(x);
}
static __device__ __forceinline__ float exp2_fast(float x) {
#if __has_builtin(__builtin_amdgcn_exp2f)
    return __builtin_amdgcn_exp2f(x);   // v_exp_f32
#else
    return exp2f(x);
#endif
}
// sigmoid(z) with z pre-scaled by log2(e): s = 1/(1+2^(-z2)); t = -z2
static __device__ __forceinline__ float sig_from_t(float t) {
    return rcpf(1.0f + exp2_fast(t));
}

// 4 rows of sigmoid-synapse accumulate for one (i,h) pack element.
static __device__ __forceinline__ void rows4(const float4 p, const float4 vv,
                                             float num[4], float den[4]) {
    float s;
    s = sig_from_t(fmaf(-p.y, vv.x, p.z));
    num[0] = fmaf(s, p.w, num[0]); den[0] = fmaf(s, p.x, den[0]);
    s = sig_from_t(fmaf(-p.y, vv.y, p.z));
    num[1] = fmaf(s, p.w, num[1]); den[1] = fmaf(s, p.x, den[1]);
    s = sig_from_t(fmaf(-p.y, vv.z, p.z));
    num[2] = fmaf(s, p.w, num[2]); den[2] = fmaf(s, p.x, den[2]);
    s = sig_from_t(fmaf(-p.y, vv.w, p.z));
    num[3] = fmaf(s, p.w, num[3]); den[3] = fmaf(s, p.x, den[3]);
}

// ---------------------------------------------------------------------------
// Prep: (a) pack {relu(w), sig*L2E, sig*mu*L2E, relu(w)*erev} into float4 for
// the three hot matrices; (b) layer-0 input synapse sums [B,H0] (x is shared
// by all K particles and all 6 steps). One kernel, branch on blockIdx.
constexpr int NPACK    = H0 * H0 + H0 * H1 + H1 * H1;  // 53248
constexpr int NPACKBLK = NPACK / 256;                   // 208
__global__ __launch_bounds__(256) void prep_kernel(
    const float* __restrict__ w0,  const float* __restrict__ sig0,
    const float* __restrict__ mu0, const float* __restrict__ erev0,
    const float* __restrict__ iw1, const float* __restrict__ isig1,
    const float* __restrict__ imu1,const float* __restrict__ ierev1,
    const float* __restrict__ w1,  const float* __restrict__ sig1,
    const float* __restrict__ mu1, const float* __restrict__ erev1,
    const float* __restrict__ x,   const float* __restrict__ iw0,
    const float* __restrict__ isig0,const float* __restrict__ imu0,
    const float* __restrict__ ierev0,
    float4* __restrict__ pack0, float4* __restrict__ packi1,
    float4* __restrict__ pack1,
    float* __restrict__ in_num, float* __restrict__ in_den)
{
    __shared__ float xs[IN];
    if (blockIdx.x < NPACKBLK) {
        const int t = blockIdx.x * 256 + threadIdx.x;
        constexpr int N0 = H0 * H0;          // 36864
        constexpr int N1 = H0 * H1;          // 12288
        if (t < N0) {
            const float wv = fmaxf(w0[t], 0.0f);
            pack0[t] = make_float4(wv, sig0[t] * L2E, sig0[t] * mu0[t] * L2E,
                                   wv * erev0[t]);
        } else if (t < N0 + N1) {
            const int u = t - N0;
            const float wv = fmaxf(iw1[u], 0.0f);
            packi1[u] = make_float4(wv, isig1[u] * L2E,
                                    isig1[u] * imu1[u] * L2E, wv * ierev1[u]);
        } else {
            const int u = t - N0 - N1;
            const float wv = fmaxf(w1[u], 0.0f);
            pack1[u] = make_float4(wv, sig1[u] * L2E, sig1[u] * mu1[u] * L2E,
                                   wv * erev1[u]);
        }
    } else {
        const int b = blockIdx.x - NPACKBLK;
        const int h = threadIdx.x;
        if (h < IN) xs[h] = x[b * IN + h];
        __syncthreads();
        if (h < H0) {
            float num = 0.0f, den = 0.0f;
            #pragma unroll 4
            for (int i = 0; i < IN; ++i) {
                const int idx = i * H0 + h;
                const float wv = fmaxf(iw0[idx], 0.0f);
                const float t  = isig0[idx] * L2E * (imu0[idx] - xs[i]);
                const float a  = wv * sig_from_t(t);
                num = fmaf(a, ierev0[idx], num);
                den += a;
            }
            in_num[b * H0 + h] = num;
            in_den[b * H0 + h] = den;
        }
    }
}

// ---------------------------------------------------------------------------
// Fused unfold + output: 256 blocks x 768 threads, ONE block/CU.
//
// Persistent pack values are INDIVIDUALLY NAMED float4 variables, not arrays:
// R5-R8 evidence shows per-thread float4 arrays >=128 B are lowered to
// scratch (private mem) on this toolchain — R7/R8's pr[16] produced 95 MB
// scratch WRITE_SIZE at VGPR_Count=84 regardless of launch_bounds. Named
// scalars cannot be scratch-lowered; amdgpu_waves_per_eu(3,3) additionally
// pins the occupancy target to our real 12 waves/CU (~168-VGPR budget).
//
// Layer 0: subgroup q in 0..3 (192 thr) owns i in [48q,48q+48) for ALL 4
// rows: 16 i's persistent in named regs (loaded once, reused 6 steps —
// giving each wave ~800cy of load-free work right after every barrier),
// 32 i's streamed from L2. State transposed vs[i][4] (one wave-uniform
// ds_read_b128 = all 4 rows). Partials via LDS; thread (q,h) updates row q.
// Layer 1: input-syn over s0 split 12 ways (one-shot); recurrent matrix
// fully register-resident (8 named float4, waves 0..7); update waves 0..3.
#define PR_LOAD(J)  const float4 prl##J = pp[(size_t)(J) * H0]
#define PR_USE(J)   rows4(prl##J, vs4[48 * q + (J)], num, den)
#define P1_LOAD(J)  const float4 pw1##J = p1p[(size_t)(J) * H1]
#define P1_USE(J)   rows4(pw1##J, *(const float4*)&v1s[qq * 8 + (J)][0], num, den)

__global__ __launch_bounds__(768)
__attribute__((amdgpu_waves_per_eu(3, 3)))
void fused_unfold_kernel(
    const float* __restrict__ particles,  // [BK, 256]
    const float* __restrict__ noise0,     // [UNF, BK, H0]
    const float* __restrict__ noise1,     // [UNF, BK, H1]
    const float* __restrict__ log_weights,// [B, K]
    const float* __restrict__ gleak0, const float* __restrict__ vleak0,
    const float* __restrict__ cm0,    const float* __restrict__ gdiff0,
    const float* __restrict__ gleak1, const float* __restrict__ vleak1,
    const float* __restrict__ cm1,    const float* __restrict__ gdiff1,
    const float4* __restrict__ pack0,     // [H0*H0]
    const float4* __restrict__ packi1,    // [H0*H1]
    const float4* __restrict__ pack1,     // [H1*H1]
    const float* __restrict__ in_num,     // [B, H0]
    const float* __restrict__ in_den,
    float* __restrict__ outp,             // new_particles region: [BK, 256]
    float* __restrict__ out_y,            // [B, H1] — pre-zeroed
    float* __restrict__ out_lw)           // [B, K]
{
    const int tid = threadIdx.x;
    const int h   = tid % H0;             // 0..191
    const int q   = tid / H0;             // 0..3 (i-split group == owned row)
    const int bk0 = blockIdx.x * 4;
    const int b   = blockIdx.x >> 4;      // batch (16 blocks per batch)
    const int k0  = (blockIdx.x & 15) * 4;// this block's first k within batch

    const int h1  = tid & 63;
    const int qq  = tid >> 6;             // wave id 0..11

    __shared__ __align__(16) float vs[H0][4];     // s0 state, [i][m]
    __shared__ float2 part0[4][4][H0];            // [q][m][h] {num,den}
    __shared__ __align__(16) float v1s[H1][4];    // s1 state, [i][m]
    __shared__ float2 part1[12][4][H1];           // [slot][m][h1]
    __shared__ float  w4[4];                      // softmax weights, this block

    // ---- Softmax weights + log_weights passthrough (wave 0) ----
    if (tid < 64) {
        const float lw = log_weights[b * K + tid];
        out_lw[b * K + tid] = lw;                 // 16x redundant, same value
        float mx = lw;
        #pragma unroll
        for (int o = 32; o > 0; o >>= 1) mx = fmaxf(mx, __shfl_xor(mx, o));
        const float e = __expf(lw - mx);
        float ssum = e;
        #pragma unroll
        for (int o = 32; o > 0; o >>= 1) ssum += __shfl_xor(ssum, o);
        if (tid >= k0 && tid < k0 + 4) w4[tid - k0] = e / ssum;
    }

    // ---- Early layer-1 state loads (hidden behind layer-0 compute) ----
    float nz1[UNF];
    if (tid < 256) {                      // qq in 0..3 = row
        v1s[h1][qq] = particles[(bk0 + qq) * 256 + H0 + h1];
        #pragma unroll
        for (int s = 0; s < UNF; ++s)
            nz1[s] = noise1[s * (BK * H1) + (bk0 + qq) * H1 + h1];
    }

    // ---- Layer 0 setup (all 768 threads: 4 rows x 192 h) ----
    vs[h][q] = particles[(bk0 + q) * 256 + h];
    float nz[UNF];
    #pragma unroll
    for (int s = 0; s < UNF; ++s)
        nz[s] = noise0[s * (BK * H0) + (bk0 + q) * H0 + h];

    const float gl    = fmaxf(gleak0[h], 0.0f);
    const float glvl  = gl * vleak0[h];
    const float cinv  = rcpf(fmaxf(cm0[h], 0.0f) + EPS);
    const float gd    = gdiff0[h] * sqrtf(DT);
    const float innum = in_num[b * H0 + h];
    const float inden = in_den[b * H0 + h];

    // Persistent pack registers: first 16 of this thread's 48 i's, as NAMED
    // float4s (loaded once, reused all 6 steps; pack is step-invariant).
    const float4* pp = pack0 + (size_t)(48 * q) * H0 + h;
    PR_LOAD(0);  PR_LOAD(1);  PR_LOAD(2);  PR_LOAD(3);
    PR_LOAD(4);  PR_LOAD(5);  PR_LOAD(6);  PR_LOAD(7);
    PR_LOAD(8);  PR_LOAD(9);  PR_LOAD(10); PR_LOAD(11);
    PR_LOAD(12); PR_LOAD(13); PR_LOAD(14); PR_LOAD(15);
    const float4* ps = pp + (size_t)16 * H0;      // streamed remainder (32)

    const float4* vs4 = (const float4*)&vs[0][0];
    __syncthreads();

    // ---- Layer 0 unfold ----
    for (int step = 0; step < UNF; ++step) {
        float num[4] = {0.f, 0.f, 0.f, 0.f};
        float den[4] = {0.f, 0.f, 0.f, 0.f};
        // register-resident part: issuable immediately after the barrier,
        // covers the stream loads' L2 latency
        PR_USE(0);  PR_USE(1);  PR_USE(2);  PR_USE(3);
        PR_USE(4);  PR_USE(5);  PR_USE(6);  PR_USE(7);
        PR_USE(8);  PR_USE(9);  PR_USE(10); PR_USE(11);
        PR_USE(12); PR_USE(13); PR_USE(14); PR_USE(15);
        // streamed part
        #pragma unroll 8
        for (int ii = 0; ii < 32; ++ii)
            rows4(ps[(size_t)ii * H0], vs4[48 * q + 16 + ii], num, den);

        #pragma unroll
        for (int m = 0; m < 4; ++m)
            part0[q][m][h] = make_float2(num[m], den[m]);
        __syncthreads();
        // thread (q,h) updates row q, element h — all 768 threads active
        float tn = innum, td = inden;
        #pragma unroll
        for (int j = 0; j < 4; ++j) {
            const float2 t = part0[j][q][h];
            tn += t.x; td += t.y;
        }
        const float vh = vs[h][q];
        const float d  = (glvl + tn - (gl + td) * vh) * cinv;
        vs[h][q] = fmaf(gd, nz[step], fmaf(d, DT, vh));
        __syncthreads();
    }

    // s0 -> new_particles[:, :H0] (own value; no barrier needed)
    outp[(bk0 + q) * 256 + h] = vs[h][q];

    // ---- Layer 1 (same 4 rows; s0 in LDS) ----
    const float gl1   = fmaxf(gleak1[h1], 0.0f);
    const float glvl1 = gl1 * vleak1[h1];
    const float cinv1 = rcpf(fmaxf(cm1[h1], 0.0f) + EPS);
    const float gd1   = gdiff1[h1] * sqrtf(DT);

    // l1 recurrent matrix: register-resident for waves 0..7 as NAMED float4s
    // (base clamped so waves 8..11 load in-bounds junk they never use).
    const int qc = (qq < 8) ? qq : 7;
    const float4* p1p = pack1 + (size_t)(qc * 8) * H1 + h1;
    P1_LOAD(0); P1_LOAD(1); P1_LOAD(2); P1_LOAD(3);
    P1_LOAD(4); P1_LOAD(5); P1_LOAD(6); P1_LOAD(7);

    // Input synapse over s0: 12 waves x 16 i, step-invariant.
    float in1n[4] = {0.f, 0.f, 0.f, 0.f};
    float in1d[4] = {0.f, 0.f, 0.f, 0.f};
    #pragma unroll 4
    for (int ii = 0; ii < 16; ++ii) {
        const int i = qq * 16 + ii;
        rows4(packi1[i * H1 + h1], vs4[i], in1n, in1d);
    }
    if (tid >= 512) {                     // waves 8..11: deposit once
        #pragma unroll
        for (int m = 0; m < 4; ++m)
            part1[qq][m][h1] = make_float2(in1n[m], in1d[m]);
    }
    __syncthreads();

    for (int step = 0; step < UNF; ++step) {
        if (tid < 512) {                  // waves 0..7: recurrent, 8 i each
            float num[4], den[4];
            #pragma unroll
            for (int m = 0; m < 4; ++m) { num[m] = in1n[m]; den[m] = in1d[m]; }
            P1_USE(0); P1_USE(1); P1_USE(2); P1_USE(3);
            P1_USE(4); P1_USE(5); P1_USE(6); P1_USE(7);
            #pragma unroll
            for (int m = 0; m < 4; ++m)
                part1[qq][m][h1] = make_float2(num[m], den[m]);
        }
        __syncthreads();
        if (tid < 256) {                  // row qq, element h1
            float tn = 0.f, td = 0.f;
            #pragma unroll
            for (int j = 0; j < 12; ++j) {
                const float2 t = part1[j][qq][h1];
                tn += t.x; td += t.y;
            }
            const float vh = v1s[h1][qq];
            const float d  = (glvl1 + tn - (gl1 + td) * vh) * cinv1;
            v1s[h1][qq] = fmaf(gd1, nz1[step], fmaf(d, DT, vh));
        }
        __syncthreads();
    }

    if (tid < 256)
        outp[(bk0 + qq) * 256 + H0 + h1] = v1s[h1][qq];  // s1 -> [:, H0:]

    // ---- Weighted-mean contribution of this block's 4 particles ----
    if (tid < 64) {
        const float acc = w4[0] * v1s[tid][0] + w4[1] * v1s[tid][1]
                        + w4[2] * v1s[tid][2] + w4[3] * v1s[tid][3];
        atomicAdd(&out_y[b * H1 + tid], acc);
    }
}

// ---------------------------------------------------------------------------
extern "C" void kernel_launch(void* const* d_in, const int* in_sizes, int n_in,
                              void* d_out, int out_size, void* d_ws, size_t ws_size,
                              hipStream_t stream) {
    const float* x           = (const float*)d_in[0];
    const float* particles   = (const float*)d_in[1];
    const float* log_weights = (const float*)d_in[2];
    const float* noise0      = (const float*)d_in[3];
    const float* noise1      = (const float*)d_in[4];
    const float* gleak0 = (const float*)d_in[5];
    const float* vleak0 = (const float*)d_in[6];
    const float* cm0    = (const float*)d_in[7];
    const float* iw0    = (const float*)d_in[8];
    const float* isig0  = (const float*)d_in[9];
    const float* imu0   = (const float*)d_in[10];
    const float* ierev0 = (const float*)d_in[11];
    const float* w0     = (const float*)d_in[12];
    const float* sig0   = (const float*)d_in[13];
    const float* mu0    = (const float*)d_in[14];
    const float* erev0  = (const float*)d_in[15];
    const float* gdiff0 = (const float*)d_in[16];
    const float* gleak1 = (const float*)d_in[17];
    const float* vleak1 = (const float*)d_in[18];
    const float* cm1    = (const float*)d_in[19];
    const float* iw1    = (const float*)d_in[20];
    const float* isig1  = (const float*)d_in[21];
    const float* imu1   = (const float*)d_in[22];
    const float* ierev1 = (const float*)d_in[23];
    const float* w1     = (const float*)d_in[24];
    const float* sig1   = (const float*)d_in[25];
    const float* mu1    = (const float*)d_in[26];
    const float* erev1  = (const float*)d_in[27];
    const float* gdiff1 = (const float*)d_in[28];

    float* out    = (float*)d_out;
    float* out_y  = out;                       // [B, H1] = 1024
    float* out_np = out + B * H1;              // [BK, 256] = 262144
    float* out_lw = out + B * H1 + BK * 256;   // [B, K]   = 1024

    // Workspace layout (floats): pack0 | packi1 | pack1 | in_num0 | in_den0
    float* ws      = (float*)d_ws;
    float4* pack0  = (float4*)(ws);                       // 36864 float4
    float4* packi1 = (float4*)(ws + 4 * 36864);           // 12288 float4
    float4* pack1  = (float4*)(ws + 4 * (36864 + 12288)); //  4096 float4
    float*  in_num0 = ws + 4 * (36864 + 12288 + 4096);    // [B, H0]
    float*  in_den0 = in_num0 + B * H0;                   // [B, H0]

    // out_y accumulated via atomics — zero it (d_out is poisoned pre-call).
    hipMemsetAsync(out_y, 0, B * H1 * sizeof(float), stream);

    prep_kernel<<<NPACKBLK + B, 256, 0, stream>>>(
        w0, sig0, mu0, erev0, iw1, isig1, imu1, ierev1, w1, sig1, mu1, erev1,
        x, iw0, isig0, imu0, ierev0,
        pack0, packi1, pack1, in_num0, in_den0);

    fused_unfold_kernel<<<BK / 4, 768, 0, stream>>>(
        particles, noise0, noise1, log_weights,
        gleak0, vleak0, cm0, gdiff0,
        gleak1, vleak1, cm1, gdiff1,
        pack0, packi1, pack1, in_num0, in_den0,
        out_np, out_y, out_lw);
}

// Round 10
// 193.632 us; speedup vs baseline: 1.6280x; 1.6081x over previous
//
#include <hip/hip_runtime.h>
#include <math.h>

// Problem dims
constexpr int B   = 16;
constexpr int K   = 64;
constexpr int BK  = B * K;        // 1024
constexpr int IN  = 128;
constexpr int H0  = 192;
constexpr int H1  = 64;
constexpr int UNF = 6;
constexpr float EPS = 1e-8f;
constexpr float DT  = 1.0f / 6.0f;
constexpr float L2E = 1.4426950408889634f;   // log2(e)

typedef float v2f __attribute__((ext_vector_type(2)));

static __device__ __forceinline__ float rcpf(float x) {
    return __builtin_amdgcn_rcpf(x);
}
static __device__ __forceinline__ float exp2_fast(float x) {
#if __has_builtin(__builtin_amdgcn_exp2f)
    return __builtin_amdgcn_exp2f(x);   // v_exp_f32
#else
    return exp2f(x);
#endif
}
// sigmoid(z) with z pre-scaled by log2(e): s = 1/(1+2^(-z2)); t = -z2
static __device__ __forceinline__ float sig_from_t(float t) {
    return rcpf(1.0f + exp2_fast(t));
}

// 4 rows of sigmoid-synapse accumulate for one (i,h) pack element, with rows
// paired as v2f so the 12 fma/add ops become 6 v_pk_{fma,add}_f32 (splat
// operands via op_sel — no extra movs). Trans (exp2/rcp) stay scalar: 8.
// Was 16 VALU + 8 trans; now 8 VALU + 8 trans.
static __device__ __forceinline__ void rows4pk(const float4 p, const float4 vv,
                                               v2f& n01, v2f& d01,
                                               v2f& n23, v2f& d23) {
    v2f v01; v01.x = vv.x; v01.y = vv.y;
    v2f v23; v23.x = vv.z; v23.y = vv.w;
    const v2f t01 = p.z - p.y * v01;          // v_pk_fma_f32
    const v2f t23 = p.z - p.y * v23;
    v2f e01, e23;
    e01.x = exp2_fast(t01.x); e01.y = exp2_fast(t01.y);
    e23.x = exp2_fast(t23.x); e23.y = exp2_fast(t23.y);
    const v2f o01 = e01 + 1.0f;               // v_pk_add_f32
    const v2f o23 = e23 + 1.0f;
    v2f s01, s23;
    s01.x = rcpf(o01.x); s01.y = rcpf(o01.y);
    s23.x = rcpf(o23.x); s23.y = rcpf(o23.y);
    n01 += s01 * p.w;  d01 += s01 * p.x;      // v_pk_fma_f32 (splat)
    n23 += s23 * p.w;  d23 += s23 * p.x;
}

// ---------------------------------------------------------------------------
// Prep: (a) pack {relu(w), sig*L2E, sig*mu*L2E, relu(w)*erev} into float4 for
// the three hot matrices; (b) layer-0 input synapse sums [B,H0] (x is shared
// by all K particles and all 6 steps). One kernel, branch on blockIdx.
constexpr int NPACK    = H0 * H0 + H0 * H1 + H1 * H1;  // 53248
constexpr int NPACKBLK = NPACK / 256;                   // 208
__global__ __launch_bounds__(256) void prep_kernel(
    const float* __restrict__ w0,  const float* __restrict__ sig0,
    const float* __restrict__ mu0, const float* __restrict__ erev0,
    const float* __restrict__ iw1, const float* __restrict__ isig1,
    const float* __restrict__ imu1,const float* __restrict__ ierev1,
    const float* __restrict__ w1,  const float* __restrict__ sig1,
    const float* __restrict__ mu1, const float* __restrict__ erev1,
    const float* __restrict__ x,   const float* __restrict__ iw0,
    const float* __restrict__ isig0,const float* __restrict__ imu0,
    const float* __restrict__ ierev0,
    float4* __restrict__ pack0, float4* __restrict__ packi1,
    float4* __restrict__ pack1,
    float* __restrict__ in_num, float* __restrict__ in_den)
{
    __shared__ float xs[IN];
    if (blockIdx.x < NPACKBLK) {
        const int t = blockIdx.x * 256 + threadIdx.x;
        constexpr int N0 = H0 * H0;          // 36864
        constexpr int N1 = H0 * H1;          // 12288
        if (t < N0) {
            const float wv = fmaxf(w0[t], 0.0f);
            pack0[t] = make_float4(wv, sig0[t] * L2E, sig0[t] * mu0[t] * L2E,
                                   wv * erev0[t]);
        } else if (t < N0 + N1) {
            const int u = t - N0;
            const float wv = fmaxf(iw1[u], 0.0f);
            packi1[u] = make_float4(wv, isig1[u] * L2E,
                                    isig1[u] * imu1[u] * L2E, wv * ierev1[u]);
        } else {
            const int u = t - N0 - N1;
            const float wv = fmaxf(w1[u], 0.0f);
            pack1[u] = make_float4(wv, sig1[u] * L2E, sig1[u] * mu1[u] * L2E,
                                   wv * erev1[u]);
        }
    } else {
        const int b = blockIdx.x - NPACKBLK;
        const int h = threadIdx.x;
        if (h < IN) xs[h] = x[b * IN + h];
        __syncthreads();
        if (h < H0) {
            float num = 0.0f, den = 0.0f;
            #pragma unroll 4
            for (int i = 0; i < IN; ++i) {
                const int idx = i * H0 + h;
                const float wv = fmaxf(iw0[idx], 0.0f);
                const float t  = isig0[idx] * L2E * (imu0[idx] - xs[i]);
                const float a  = wv * sig_from_t(t);
                num = fmaf(a, ierev0[idx], num);
                den += a;
            }
            in_num[b * H0 + h] = num;
            in_den[b * H0 + h] = den;
        }
    }
}

// ---------------------------------------------------------------------------
// Layer-0 sweep body: LEN i-values x 4 rows (paired), compile-time trip count.
template <int LEN>
static __device__ __forceinline__ void sweep0_body(
    const float4* __restrict__ pp,      // pack0 + ibase*H0 + h
    const float* vsbase, int ibase,     // &vs[0][0]
    v2f& n01, v2f& d01, v2f& n23, v2f& d23)
{
    #pragma unroll 8
    for (int ii = 0; ii < LEN; ++ii) {
        const float4 p  = pp[(size_t)ii * H0];        // {wv, sig', smu', wv*er}
        const float4 vv = *(const float4*)(vsbase + (ibase + ii) * 4);
        rows4pk(p, vv, n01, d01, n23, d23);
    }
}

// ---------------------------------------------------------------------------
// Fused unfold + output: 256 blocks x 960 threads (15 waves, one block/CU;
// R4 showed the HW does not co-schedule two 12-wave blocks; R6-R9 showed
// per-thread working sets beyond the ~84-VGPR allocator target spill to
// scratch regardless of launch-bounds/waves_per_eu — so this kernel keeps
// the R5 streaming structure, VGPR~64, zero scratch).
//
// Layer 0: subgroup q in 0..4 (192 thr each) handles i-range {40,40,40,40,32}
// for ALL 4 rows; state transposed vs[i][4] (one wave-uniform ds_read_b128 =
// all 4 rows); rows paired for v_pk_fma_f32. Partials via LDS; q<4 threads
// apply row q's update.
// Layer 1: waves 0..7 split i 8-ways with the same pairing.
// Output: per-block softmax over the batch's 64 log-weights, atomicAdd of
// this block's 4-row contribution into out_y (zeroed by hipMemsetAsync).
__global__ __launch_bounds__(960) void fused_unfold_kernel(
    const float* __restrict__ particles,  // [BK, 256]
    const float* __restrict__ noise0,     // [UNF, BK, H0]
    const float* __restrict__ noise1,     // [UNF, BK, H1]
    const float* __restrict__ log_weights,// [B, K]
    const float* __restrict__ gleak0, const float* __restrict__ vleak0,
    const float* __restrict__ cm0,    const float* __restrict__ gdiff0,
    const float* __restrict__ gleak1, const float* __restrict__ vleak1,
    const float* __restrict__ cm1,    const float* __restrict__ gdiff1,
    const float4* __restrict__ pack0,     // [H0*H0]
    const float4* __restrict__ packi1,    // [H0*H1]
    const float4* __restrict__ pack1,     // [H1*H1]
    const float* __restrict__ in_num,     // [B, H0]
    const float* __restrict__ in_den,
    float* __restrict__ outp,             // new_particles region: [BK, 256]
    float* __restrict__ out_y,            // [B, H1] — pre-zeroed
    float* __restrict__ out_lw)           // [B, K]
{
    const int tid = threadIdx.x;
    const int h   = tid % H0;             // 0..191
    const int q   = tid / H0;             // 0..4 (i-split group; q<4 also row)
    const int bk0 = blockIdx.x * 4;
    const int b   = blockIdx.x >> 4;      // batch (16 blocks per batch)
    const int k0  = (blockIdx.x & 15) * 4;// this block's first k within batch

    const int h1  = tid & 63;
    const int qq  = tid >> 6;             // wave id 0..14

    __shared__ __align__(16) float vs[H0][4];     // s0 state, [i][m]
    __shared__ float2 part0[5][4][H0];            // [q][m][h] {num,den}
    __shared__ __align__(16) float v1s[H1][4];    // s1 state, [i][m]
    __shared__ float2 part1[8][4][H1];            // [qq][m][h1]
    __shared__ float  w4[4];                      // softmax weights, this block

    // ---- Softmax weights + log_weights passthrough (wave 0) ----
    if (tid < 64) {
        const float lw = log_weights[b * K + tid];
        out_lw[b * K + tid] = lw;                 // 16x redundant, same value
        float mx = lw;
        #pragma unroll
        for (int o = 32; o > 0; o >>= 1) mx = fmaxf(mx, __shfl_xor(mx, o));
        const float e = __expf(lw - mx);
        float ssum = e;
        #pragma unroll
        for (int o = 32; o > 0; o >>= 1) ssum += __shfl_xor(ssum, o);
        if (tid >= k0 && tid < k0 + 4) w4[tid - k0] = e / ssum;
    }

    // ---- Early layer-1 state loads (hidden behind layer-0 compute) ----
    float nz1[UNF];
    if (tid < 256) {                      // qq in 0..3 = row
        v1s[h1][qq] = particles[(bk0 + qq) * 256 + H0 + h1];
        #pragma unroll
        for (int s = 0; s < UNF; ++s)
            nz1[s] = noise1[s * (BK * H1) + (bk0 + qq) * H1 + h1];
    }

    // ---- Layer 0 setup ----
    float nz[UNF];
    if (q < 4) {
        vs[h][q] = particles[(bk0 + q) * 256 + h];
        #pragma unroll
        for (int s = 0; s < UNF; ++s)
            nz[s] = noise0[s * (BK * H0) + (bk0 + q) * H0 + h];
    }

    const float gl    = fmaxf(gleak0[h], 0.0f);
    const float glvl  = gl * vleak0[h];
    const float cinv  = rcpf(fmaxf(cm0[h], 0.0f) + EPS);
    const float gd    = gdiff0[h] * sqrtf(DT);
    const float innum = in_num[b * H0 + h];
    const float inden = in_den[b * H0 + h];
    __syncthreads();

    // ---- Layer 0 unfold ----
    const int ibase = (q == 4) ? 160 : 40 * q;
    const float4* pp = pack0 + (size_t)ibase * H0 + h;
    for (int step = 0; step < UNF; ++step) {
        v2f n01 = {0.f, 0.f}, d01 = {0.f, 0.f};
        v2f n23 = {0.f, 0.f}, d23 = {0.f, 0.f};
        if (q == 4) sweep0_body<32>(pp, &vs[0][0], ibase, n01, d01, n23, d23);
        else        sweep0_body<40>(pp, &vs[0][0], ibase, n01, d01, n23, d23);
        part0[q][0][h] = make_float2(n01.x, d01.x);
        part0[q][1][h] = make_float2(n01.y, d01.y);
        part0[q][2][h] = make_float2(n23.x, d23.x);
        part0[q][3][h] = make_float2(n23.y, d23.y);
        __syncthreads();
        if (q < 4) {                      // thread (q,h) updates row q
            float tn = innum, td = inden;
            #pragma unroll
            for (int j = 0; j < 5; ++j) {
                const float2 t = part0[j][q][h];
                tn += t.x; td += t.y;
            }
            const float vh = vs[h][q];
            const float d  = (glvl + tn - (gl + td) * vh) * cinv;
            vs[h][q] = fmaf(gd, nz[step], fmaf(d, DT, vh));
        }
        __syncthreads();
    }

    // s0 -> new_particles[:, :H0] (own value; no barrier needed)
    if (q < 4) outp[(bk0 + q) * 256 + h] = vs[h][q];

    // ---- Layer 1 (same 4 rows; s0 in LDS) ----
    float gl1 = 0.f, glvl1 = 0.f, cinv1 = 0.f, gd1 = 0.f;
    v2f i1n01 = {0.f, 0.f}, i1d01 = {0.f, 0.f};
    v2f i1n23 = {0.f, 0.f}, i1d23 = {0.f, 0.f};
    const float* vsbase = &vs[0][0];
    if (tid < 512) {                      // waves 0..7: i-split over 192
        gl1   = fmaxf(gleak1[h1], 0.0f);
        glvl1 = gl1 * vleak1[h1];
        cinv1 = rcpf(fmaxf(cm1[h1], 0.0f) + EPS);
        gd1   = gdiff1[h1] * sqrtf(DT);
        #pragma unroll 4
        for (int ii = 0; ii < 24; ++ii) {
            const int i = qq * 24 + ii;
            const float4 p  = packi1[i * H1 + h1];
            const float4 vv = *(const float4*)(vsbase + i * 4);
            rows4pk(p, vv, i1n01, i1d01, i1n23, i1d23);
        }
    }
    __syncthreads();   // v1s visible

    for (int step = 0; step < UNF; ++step) {
        if (tid < 512) {
            v2f n01 = i1n01, d01 = i1d01, n23 = i1n23, d23 = i1d23;
            #pragma unroll
            for (int ii = 0; ii < 8; ++ii) {
                const int i = qq * 8 + ii;
                const float4 p  = pack1[i * H1 + h1];
                const float4 vv = *(const float4*)&v1s[i][0];
                rows4pk(p, vv, n01, d01, n23, d23);
            }
            part1[qq][0][h1] = make_float2(n01.x, d01.x);
            part1[qq][1][h1] = make_float2(n01.y, d01.y);
            part1[qq][2][h1] = make_float2(n23.x, d23.x);
            part1[qq][3][h1] = make_float2(n23.y, d23.y);
        }
        __syncthreads();
        if (tid < 256) {                  // row qq, element h1
            float tn = 0.f, td = 0.f;
            #pragma unroll
            for (int j = 0; j < 8; ++j) {
                const float2 t = part1[j][qq][h1];
                tn += t.x; td += t.y;
            }
            const float vh = v1s[h1][qq];
            const float d  = (glvl1 + tn - (gl1 + td) * vh) * cinv1;
            v1s[h1][qq] = fmaf(gd1, nz1[step], fmaf(d, DT, vh));
        }
        __syncthreads();
    }

    if (tid < 256)
        outp[(bk0 + qq) * 256 + H0 + h1] = v1s[h1][qq];  // s1 -> [:, H0:]

    // ---- Weighted-mean contribution of this block's 4 particles ----
    if (tid < 64) {
        const float acc = w4[0] * v1s[tid][0] + w4[1] * v1s[tid][1]
                        + w4[2] * v1s[tid][2] + w4[3] * v1s[tid][3];
        atomicAdd(&out_y[b * H1 + tid], acc);
    }
}

// ---------------------------------------------------------------------------
extern "C" void kernel_launch(void* const* d_in, const int* in_sizes, int n_in,
                              void* d_out, int out_size, void* d_ws, size_t ws_size,
                              hipStream_t stream) {
    const float* x           = (const float*)d_in[0];
    const float* particles   = (const float*)d_in[1];
    const float* log_weights = (const float*)d_in[2];
    const float* noise0      = (const float*)d_in[3];
    const float* noise1      = (const float*)d_in[4];
    const float* gleak0 = (const float*)d_in[5];
    const float* vleak0 = (const float*)d_in[6];
    const float* cm0    = (const float*)d_in[7];
    const float* iw0    = (const float*)d_in[8];
    const float* isig0  = (const float*)d_in[9];
    const float* imu0   = (const float*)d_in[10];
    const float* ierev0 = (const float*)d_in[11];
    const float* w0     = (const float*)d_in[12];
    const float* sig0   = (const float*)d_in[13];
    const float* mu0    = (const float*)d_in[14];
    const float* erev0  = (const float*)d_in[15];
    const float* gdiff0 = (const float*)d_in[16];
    const float* gleak1 = (const float*)d_in[17];
    const float* vleak1 = (const float*)d_in[18];
    const float* cm1    = (const float*)d_in[19];
    const float* iw1    = (const float*)d_in[20];
    const float* isig1  = (const float*)d_in[21];
    const float* imu1   = (const float*)d_in[22];
    const float* ierev1 = (const float*)d_in[23];
    const float* w1     = (const float*)d_in[24];
    const float* sig1   = (const float*)d_in[25];
    const float* mu1    = (const float*)d_in[26];
    const float* erev1  = (const float*)d_in[27];
    const float* gdiff1 = (const float*)d_in[28];

    float* out    = (float*)d_out;
    float* out_y  = out;                       // [B, H1] = 1024
    float* out_np = out + B * H1;              // [BK, 256] = 262144
    float* out_lw = out + B * H1 + BK * 256;   // [B, K]   = 1024

    // Workspace layout (floats): pack0 | packi1 | pack1 | in_num0 | in_den0
    float* ws      = (float*)d_ws;
    float4* pack0  = (float4*)(ws);                       // 36864 float4
    float4* packi1 = (float4*)(ws + 4 * 36864);           // 12288 float4
    float4* pack1  = (float4*)(ws + 4 * (36864 + 12288)); //  4096 float4
    float*  in_num0 = ws + 4 * (36864 + 12288 + 4096);    // [B, H0]
    float*  in_den0 = in_num0 + B * H0;                   // [B, H0]

    // out_y accumulated via atomics — zero it (d_out is poisoned pre-call).
    hipMemsetAsync(out_y, 0, B * H1 * sizeof(float), stream);

    prep_kernel<<<NPACKBLK + B, 256, 0, stream>>>(
        w0, sig0, mu0, erev0, iw1, isig1, imu1, ierev1, w1, sig1, mu1, erev1,
        x, iw0, isig0, imu0, ierev0,
        pack0, packi1, pack1, in_num0, in_den0);

    fused_unfold_kernel<<<BK / 4, 960, 0, stream>>>(
        particles, noise0, noise1, log_weights,
        gleak0, vleak0, cm0, gdiff0,
        gleak1, vleak1, cm1, gdiff1,
        pack0, packi1, pack1, in_num0, in_den0,
        out_np, out_y, out_lw);
}